// Round 12
// baseline (166.511 us; speedup 1.0000x reference)
//
#include <hip/hip_runtime.h>
#include <math.h>

#define B_      64
#define S_      128
#define KN      16
#define EE      128
#define HH      100
#define NTREE   8192            // B_*S_

typedef __attribute__((ext_vector_type(8))) short   bf8;    // 8 bf16 (4 VGPRs)
typedef __attribute__((ext_vector_type(4))) float   f32x4;
typedef __attribute__((ext_vector_type(8))) float   f32x8;
typedef __attribute__((ext_vector_type(4))) unsigned int u32x4;

// workspace byte offsets (256-aligned)
#define WC_BF_OFF    12800000u    // 128*128*2   = 32,768
#define WIH_BF_OFF   12832768u    // 768*128*2   = 196,608 (padded [dir][g][128j][128k])
#define WHH_BF_OFF   13029376u    // 768*128*2   = 196,608 (padded, zero pads)
#define ENC_BF_OFF   13225984u    // 16384*128*2 = 4,194,304   rows = e*8192 + t*64 + b
#define HMAX_OFF     17420288u    // 25600*4     = 102,400

__constant__ float c_cnt[16] = {16.f,8.f,7.f,4.f,3.f,3.f,3.f,2.f,
                                1.f,1.f,1.f,1.f,1.f,1.f,1.f,1.f};

__device__ __forceinline__ float bf2f(unsigned short u) {
    unsigned int x = ((unsigned int)u) << 16;
    return __builtin_bit_cast(float, x);
}
__device__ __forceinline__ unsigned short f2bf(float f) {
    unsigned int x = __builtin_bit_cast(unsigned int, f);
    x = x + 0x7fffu + ((x >> 16) & 1u);          // RNE
    return (unsigned short)(x >> 16);
}
__device__ __forceinline__ f32x8 shx(const f32x8& v, int m) {
    f32x8 o;
    #pragma unroll
    for (int q = 0; q < 8; ++q) o[q] = __shfl_xor(v[q], m);
    return o;
}
__device__ __forceinline__ bf8 pack8(const f32x8& v) {
    bf8 o;
    #pragma unroll
    for (int q = 0; q < 8; ++q) o[q] = (short)f2bf(v[q]);
    return o;
}
__device__ __forceinline__ float selq(const f32x4& v, int q) {
    const float a = (q & 1) ? v[1] : v[0];
    const float b = (q & 1) ? v[3] : v[2];
    return (q & 2) ? b : a;
}
// swizzle a 16B-aligned column-byte offset within a 256B row
#define SWZ(row, cb) ((cb) ^ (((row) & 7) << 4))

// ---------------------------------------------------------------------------
// K0: fp32 -> bf16 prep of Wc + wih/whh padded [2][3][128j][128k] (zero pads).
// emb stays fp32 (k_encode gathers directly).
// ---------------------------------------------------------------------------
#define NB 4096      // Wc float4s
#define NC 24576     // wih_pad ushort4s (768*128/4)
#define ND 24576     // whh_pad ushort4s
__global__ __launch_bounds__(256) void k_prep(
    const float* __restrict__ Wc,
    const float* __restrict__ wih_f, const float* __restrict__ wih_b,
    const float* __restrict__ whh_f, const float* __restrict__ whh_b,
    unsigned short* __restrict__ wc_bf,
    unsigned short* __restrict__ wih_pad, unsigned short* __restrict__ whh_pad)
{
    const int i = blockIdx.x * 256 + threadIdx.x;
    if (i < NB) {
        float4 v = ((const float4*)Wc)[i];
        ushort4 o;
        o.x = f2bf(v.x); o.y = f2bf(v.y); o.z = f2bf(v.z); o.w = f2bf(v.w);
        ((ushort4*)wc_bf)[i] = o;
    } else if (i < NB + NC) {
        const int u = i - NB;                       // 0..24575
        const int row = u >> 5, k4 = u & 31;        // row 0..767
        const int dir = row / 384, rem = row % 384, g = rem >> 7, j = rem & 127;
        ushort4 o = {0, 0, 0, 0};
        if (j < 100) {
            const float* w = dir ? wih_b : wih_f;   // [300][128]
            float4 v = ((const float4*)w)[(g * 100 + j) * 32 + k4];
            o.x = f2bf(v.x); o.y = f2bf(v.y); o.z = f2bf(v.z); o.w = f2bf(v.w);
        }
        ((ushort4*)wih_pad)[u] = o;
    } else if (i < NB + NC + ND) {
        const int u = i - NB - NC;
        const int row = u >> 5, k0 = (u & 31) * 4;
        const int dir = row / 384, rem = row % 384, g = rem >> 7, j = rem & 127;
        ushort4 o = {0, 0, 0, 0};
        if (j < 100) {
            const float* w = dir ? whh_b : whh_f;   // [300][100]
            const float* wr = w + (g * 100 + j) * 100;
            unsigned short t[4];
            #pragma unroll
            for (int q = 0; q < 4; ++q)
                t[q] = (k0 + q < 100) ? f2bf(wr[k0 + q]) : (unsigned short)0;
            o.x = t[0]; o.y = t[1]; o.z = t[2]; o.w = t[3];
        }
        ((ushort4*)whh_pad)[u] = o;
    }
}

// ---------------------------------------------------------------------------
// K1: gather fp32 emb directly (2 x float4 / node) -> shfl tree aggregation
// -> bf16 A tile; B = Wc bf16. MFMA 16x16x32; epilogue: +cnt*bc, per-tree
// max, relu. enc rows stored e*8192 + t*64 + b.
// ---------------------------------------------------------------------------
__global__ __launch_bounds__(512) void k_encode(
    const int* __restrict__ tok1, const int* __restrict__ tok2,
    const float* __restrict__ emb,
    const unsigned short* __restrict__ wc_bf,
    const float* __restrict__ bc,
    unsigned short* __restrict__ enc_bf)
{
    __shared__ unsigned short A_lds[128 * 128];   // [row][k] swizzled (32KB)
    __shared__ unsigned short B_lds[128 * 128];   // [col][k] swizzled (32KB)
    const int tid = threadIdx.x;
    const int blk = blockIdx.x;
    const int e = blk >> 10;
    const int tree0 = (blk & 1023) * 8;
    const int* __restrict__ tok = e ? tok2 : tok1;

    const int lane = tid & 63;
    const int tr  = tid >> 6;        // tree 0..7 (== wave)
    const int ng  = lane >> 4;       // node group: nodes ng*4..ng*4+3
    const int seg = lane & 15;       // 8-dim segment

    u32x4 wcv[4];
    #pragma unroll
    for (int it = 0; it < 4; ++it) {
        const int idx = tid + 512 * it;          // 0..2047
        wcv[it] = *(const u32x4*)(wc_bf + (idx >> 4) * EE + (idx & 15) * 8);
    }

    const int tb = (tree0 + tr) * KN + ng * 4;
    const int tk0 = tok[tb + 0], tk1 = tok[tb + 1], tk2 = tok[tb + 2], tk3 = tok[tb + 3];
    f32x8 a0, a1, a2, a3;
    {
        #define LD8(dst, tk)                                                   \
        {                                                                      \
            const float* p = emb + (size_t)(tk) * EE + seg * 8;                \
            float4 lo = *(const float4*)p;                                     \
            float4 hi = *(const float4*)(p + 4);                               \
            dst[0] = lo.x; dst[1] = lo.y; dst[2] = lo.z; dst[3] = lo.w;        \
            dst[4] = hi.x; dst[5] = hi.y; dst[6] = hi.z; dst[7] = hi.w;        \
        }
        LD8(a0, tk0) LD8(a1, tk1) LD8(a2, tk2) LD8(a3, tk3)
        #undef LD8
    }

    {
        f32x8 t0 = shx(a3, 32);
        if (ng == 1) a3 += t0;
        f32x8 u1 = shx(a3, 16), u2 = shx(a0, 32);
        if (ng == 0) a3 += u1 + u2;
        f32x8 v1 = shx(a1, 48), v2 = shx(a2, 48);
        if (ng == 1) a0 += v1 + v2;
        f32x8 w1 = shx(a3, 48), w2 = shx(a0, 32);
        if (ng == 1) a1 += w1 + w2;
        f32x8 x1 = shx(a1, 32), x2 = shx(a2, 32);
        if (ng == 1) a2 += x1 + x2;
        f32x8 z1 = shx(a0, 16);
        if (ng == 0) a1 += a3 + z1;
        f32x8 z2 = shx(a1, 16), z3 = shx(a2, 16);
        if (ng == 0) a2 += z2 + z3;
        if (ng == 0) a0 += a1 + a2;
    }

    {
        const int r0 = tr * 16 + ng * 4;
        *(bf8*)((char*)A_lds + (r0+0) * 256 + SWZ(r0+0, seg * 16)) = pack8(a0);
        *(bf8*)((char*)A_lds + (r0+1) * 256 + SWZ(r0+1, seg * 16)) = pack8(a1);
        *(bf8*)((char*)A_lds + (r0+2) * 256 + SWZ(r0+2, seg * 16)) = pack8(a2);
        *(bf8*)((char*)A_lds + (r0+3) * 256 + SWZ(r0+3, seg * 16)) = pack8(a3);
    }
    #pragma unroll
    for (int it = 0; it < 4; ++it) {
        const int idx = tid + 512 * it;
        const int row = idx >> 4, sg = idx & 15;
        *(u32x4*)((char*)B_lds + row * 256 + SWZ(row, sg * 16)) = wcv[it];
    }
    __syncthreads();

    const int wid = tid >> 6;
    const int wr = wid >> 1, wc = wid & 1;
    const int l15 = lane & 15, lg = lane >> 4;

    f32x4 acc[2][4];
    #pragma unroll
    for (int rt = 0; rt < 2; ++rt)
        #pragma unroll
        for (int ct = 0; ct < 4; ++ct) acc[rt][ct] = (f32x4){0.f, 0.f, 0.f, 0.f};

    #pragma unroll
    for (int ks = 0; ks < 4; ++ks) {
        bf8 aF[2], bF[4];
        #pragma unroll
        for (int rt = 0; rt < 2; ++rt) {
            const int row = wr * 32 + rt * 16 + l15;
            aF[rt] = *(const bf8*)((const char*)A_lds + row * 256 + SWZ(row, ks * 64 + lg * 16));
        }
        #pragma unroll
        for (int ct = 0; ct < 4; ++ct) {
            const int col = wc * 64 + ct * 16 + l15;
            bF[ct] = *(const bf8*)((const char*)B_lds + col * 256 + SWZ(col, ks * 64 + lg * 16));
        }
        #pragma unroll
        for (int rt = 0; rt < 2; ++rt)
            #pragma unroll
            for (int ct = 0; ct < 4; ++ct)
                acc[rt][ct] = __builtin_amdgcn_mfma_f32_16x16x32_bf16(aF[rt], bF[ct], acc[rt][ct], 0, 0, 0);
    }

    #pragma unroll
    for (int rt = 0; rt < 2; ++rt) {
        const int ltree = wr * 2 + rt;
        #pragma unroll
        for (int ct = 0; ct < 4; ++ct) {
            const int col = wc * 64 + ct * 16 + l15;
            const float bcv = bc[col];
            f32x4 v = acc[rt][ct];
            float m = -1e30f;
            #pragma unroll
            for (int r = 0; r < 4; ++r)
                m = fmaxf(m, v[r] + c_cnt[lg * 4 + r] * bcv);
            m = fmaxf(m, __shfl_xor(m, 16));
            m = fmaxf(m, __shfl_xor(m, 32));
            m = fmaxf(m, 0.f);
            if (lg == 0) {
                const int gtree = tree0 + ltree;
                const int row = (gtree & 127) * 64 + (gtree >> 7);   // t*64 + b
                enc_bf[((size_t)e * NTREE + row) * EE + col] = f2bf(m);
            }
        }
    }
}

// ---------------------------------------------------------------------------
// K3: LDS-resident GRU scan. 64 blocks x 256 thr (4 waves, 1 wave/SIMD,
// 512-VGPR budget). Each wave owns TWO j-tiles (jb0 = w*16, jb1 = 64+w*16);
// eF/hF B-operands are SHARED across tiles -> per-CU LDS reads halve
// (56 -> 32 b128/step). eF prefetched one step ahead (enc_lds is read-only
// after staging -> no hazard; retires before the h-write's lgkmcnt(0)).
// Gate split q=l15>>2: 1 gate-unit per lane per tile, scalar gates.
// ---------------------------------------------------------------------------
__global__ __launch_bounds__(256, 1) void k_gru(
    const unsigned short* __restrict__ enc_bf,
    const unsigned short* __restrict__ wih_pad,
    const unsigned short* __restrict__ whh_pad,
    const float* __restrict__ bih_f, const float* __restrict__ bih_b,
    const float* __restrict__ bhh_f, const float* __restrict__ bhh_b,
    float* __restrict__ hmax_out)
{
    __shared__ unsigned char enc_lds[4 * 128 * 256];  // 128KB [c][t][chunk^(c<<2)]
    __shared__ unsigned char h_lds[2][4 * 256];       // 2KB dbuf, rotated chunks
    const int tid  = threadIdx.x;
    const int blk  = blockIdx.x;        // 64
    const int e    = blk >> 5;
    const int dir  = (blk >> 4) & 1;
    const int b0   = (blk & 15) * 4;
    const int lane = tid & 63;
    const int l15  = lane & 15;
    const int lg   = lane >> 4;
    const int c    = l15 & 3;           // seq column
    const int q    = l15 >> 2;          // owned r-slot (gate split)
    const int w    = tid >> 6;          // 0..3
    const int jb0  = w * 16;
    const int jb1  = 64 + w * 16;       // wave3: j 112..127 = pad (zeros, harmless)
    const int j0   = jb0 + lg * 4 + q;
    const int j1   = jb1 + lg * 4 + q;

    if (tid < 128)
        ((u32x4*)h_lds)[tid] = (u32x4){0u, 0u, 0u, 0u};

    // stage enc slice (4 seq x 128 t x 256B), content chunk = rc ^ (c<<2)
    #pragma unroll
    for (int i = 0; i < 32; ++i) {
        const int s = tid + i * 256;
        const int sc = s >> 11, st = (s >> 4) & 127, rc = s & 15;
        const int gch = rc ^ (sc << 2);
        const u32x4 v = *(const u32x4*)(enc_bf
            + ((size_t)e * NTREE + st * 64 + b0 + sc) * EE + gch * 8);
        *(u32x4*)(enc_lds + s * 16) = v;
    }

    // weight A-frags, both tiles: row j = jb + l15, k = ks*32 + lg*8
    bf8 aI0[3][4], aH0[3][4], aI1[3][4], aH1[3][4];
    {
        const unsigned short* wiP = wih_pad + (size_t)dir * 3 * 128 * 128;
        const unsigned short* whP = whh_pad + (size_t)dir * 3 * 128 * 128;
        #pragma unroll
        for (int g = 0; g < 3; ++g)
            #pragma unroll
            for (int ks = 0; ks < 4; ++ks) {
                const size_t r0 = (size_t)(g * 128 + jb0 + l15) * 128 + ks * 32 + lg * 8;
                const size_t r1 = (size_t)(g * 128 + jb1 + l15) * 128 + ks * 32 + lg * 8;
                aI0[g][ks] = *(const bf8*)(wiP + r0);
                aH0[g][ks] = *(const bf8*)(whP + r0);
                aI1[g][ks] = *(const bf8*)(wiP + r1);
                aH1[g][ks] = *(const bf8*)(whP + r1);
            }
    }
    const float* __restrict__ bih = dir ? bih_b : bih_f;
    const float* __restrict__ bhh = dir ? bhh_b : bhh_f;
    f32x4 bR0, bZ0, bI0, bH0, bR1, bZ1, bI1, bH1;
    #pragma unroll
    for (int r = 0; r < 4; ++r) {
        const int ja = jb0 + lg * 4 + r;
        const int jb = jb1 + lg * 4 + r;
        bR0[r] = (ja < 100) ? bih[ja]       + bhh[ja]       : 0.f;
        bZ0[r] = (ja < 100) ? bih[100 + ja] + bhh[100 + ja] : 0.f;
        bI0[r] = (ja < 100) ? bih[200 + ja] : 0.f;
        bH0[r] = (ja < 100) ? bhh[200 + ja] : 0.f;
        bR1[r] = (jb < 100) ? bih[jb]       + bhh[jb]       : 0.f;
        bZ1[r] = (jb < 100) ? bih[100 + jb] + bhh[100 + jb] : 0.f;
        bI1[r] = (jb < 100) ? bih[200 + jb] : 0.f;
        bH1[r] = (jb < 100) ? bhh[200 + jb] : 0.f;
    }

    // constant per-lane LDS offsets
    unsigned int eoff[4], hoff[4];
    #pragma unroll
    for (int ks = 0; ks < 4; ++ks) {
        eoff[ks] = c * 32768 + ((((ks * 4 + lg) ^ (c << 2)) & 15) << 4);
        hoff[ks] = c * 256 + (((ks * 4 + lg + 4 * c) & 15) << 4);
    }
    const unsigned int hw0 = c * 256 + ((((j0 >> 3) + 4 * c) & 15) << 4) + (j0 & 7) * 2;
    const unsigned int hw1 = c * 256 + ((((j1 >> 3) + 4 * c) & 15) << 4) + (j1 & 7) * 2;

    float h0 = 0.f, h1 = 0.f;
    float mx0 = -1e30f, mx1 = -1e30f;
    __syncthreads();   // staging + h-zero complete (one-time drain)

    bf8 eC[4], eN[4];
    {
        const int tm = dir ? 127 : 0;
        #pragma unroll
        for (int ks = 0; ks < 4; ++ks)
            eC[ks] = *(const bf8*)(enc_lds + tm * 256 + eoff[ks]);
    }

#define L2E  1.4426950408889634f
#define GRU_STEP(EC, EN, P, S)                                                 \
    {                                                                          \
        bf8 hF[4];                                                             \
        _Pragma("unroll")                                                      \
        for (int ks = 0; ks < 4; ++ks)                                         \
            hF[ks] = *(const bf8*)(h_lds[P] + hoff[ks]);                       \
        f32x4 r0 = bR0, z0 = bZ0, i0 = bI0;                                    \
        f32x4 r1 = bR1, z1 = bZ1, i1 = bI1;                                    \
        _Pragma("unroll")                                                      \
        for (int ks = 0; ks < 4; ++ks) {                                       \
            r0 = __builtin_amdgcn_mfma_f32_16x16x32_bf16(aI0[0][ks], EC[ks], r0, 0, 0, 0); \
            r1 = __builtin_amdgcn_mfma_f32_16x16x32_bf16(aI1[0][ks], EC[ks], r1, 0, 0, 0); \
            z0 = __builtin_amdgcn_mfma_f32_16x16x32_bf16(aI0[1][ks], EC[ks], z0, 0, 0, 0); \
            z1 = __builtin_amdgcn_mfma_f32_16x16x32_bf16(aI1[1][ks], EC[ks], z1, 0, 0, 0); \
            i0 = __builtin_amdgcn_mfma_f32_16x16x32_bf16(aI0[2][ks], EC[ks], i0, 0, 0, 0); \
            i1 = __builtin_amdgcn_mfma_f32_16x16x32_bf16(aI1[2][ks], EC[ks], i1, 0, 0, 0); \
        }                                                                      \
        /* prefetch next step's enc (read-only LDS; retires before lgkm(0)) */ \
        if ((S) + 1 < S_) {                                                    \
            const int tmn = dir ? (126 - (S)) : ((S) + 1);                     \
            _Pragma("unroll")                                                  \
            for (int ks = 0; ks < 4; ++ks)                                     \
                EN[ks] = *(const bf8*)(enc_lds + tmn * 256 + eoff[ks]);        \
        }                                                                      \
        f32x4 n0 = bH0, n1 = bH1;                                              \
        _Pragma("unroll")                                                      \
        for (int ks = 0; ks < 4; ++ks) {                                       \
            r0 = __builtin_amdgcn_mfma_f32_16x16x32_bf16(aH0[0][ks], hF[ks], r0, 0, 0, 0); \
            r1 = __builtin_amdgcn_mfma_f32_16x16x32_bf16(aH1[0][ks], hF[ks], r1, 0, 0, 0); \
            z0 = __builtin_amdgcn_mfma_f32_16x16x32_bf16(aH0[1][ks], hF[ks], z0, 0, 0, 0); \
            z1 = __builtin_amdgcn_mfma_f32_16x16x32_bf16(aH1[1][ks], hF[ks], z1, 0, 0, 0); \
            n0 = __builtin_amdgcn_mfma_f32_16x16x32_bf16(aH0[2][ks], hF[ks], n0, 0, 0, 0); \
            n1 = __builtin_amdgcn_mfma_f32_16x16x32_bf16(aH1[2][ks], hF[ks], n1, 0, 0, 0); \
        }                                                                      \
        {                                                                      \
            const float gr = selq(r0, q), gz = selq(z0, q);                    \
            const float gi = selq(i0, q), gh = selq(n0, q);                    \
            const float rg = __builtin_amdgcn_rcpf(1.f + __builtin_amdgcn_exp2f(-L2E * gr)); \
            const float zg = __builtin_amdgcn_rcpf(1.f + __builtin_amdgcn_exp2f(-L2E * gz)); \
            const float nx = gi + rg * gh;                                     \
            const float ng = 1.f - 2.f * __builtin_amdgcn_rcpf(1.f + __builtin_amdgcn_exp2f((2.f * L2E) * nx)); \
            h0 = ng + zg * (h0 - ng);                                          \
            mx0 = fmaxf(mx0, h0);                                              \
            *(unsigned short*)(h_lds[(P) ^ 1] + hw0) = f2bf(h0);               \
        }                                                                      \
        {                                                                      \
            const float gr = selq(r1, q), gz = selq(z1, q);                    \
            const float gi = selq(i1, q), gh = selq(n1, q);                    \
            const float rg = __builtin_amdgcn_rcpf(1.f + __builtin_amdgcn_exp2f(-L2E * gr)); \
            const float zg = __builtin_amdgcn_rcpf(1.f + __builtin_amdgcn_exp2f(-L2E * gz)); \
            const float nx = gi + rg * gh;                                     \
            const float ng = 1.f - 2.f * __builtin_amdgcn_rcpf(1.f + __builtin_amdgcn_exp2f((2.f * L2E) * nx)); \
            h1 = ng + zg * (h1 - ng);                                          \
            mx1 = fmaxf(mx1, h1);                                              \
            *(unsigned short*)(h_lds[(P) ^ 1] + hw1) = f2bf(h1);               \
        }                                                                      \
        __builtin_amdgcn_sched_barrier(0);                                     \
        asm volatile("s_waitcnt lgkmcnt(0)");                                  \
        __builtin_amdgcn_s_barrier();                                          \
        __builtin_amdgcn_sched_barrier(0);                                     \
    }

    for (int t = 0; t < S_; t += 2) {
        GRU_STEP(eC, eN, 0, t)
        GRU_STEP(eN, eC, 1, t + 1)
    }
#undef GRU_STEP

    {
        const size_t base = ((size_t)((e * 2 + dir) * 64 + b0 + c)) * HH;
        if (j0 < 100) hmax_out[base + j0] = mx0;
        if (j1 < 100) hmax_out[base + j1] = mx1;
    }
}

// ---------------------------------------------------------------------------
// K4: fc + softmax
// ---------------------------------------------------------------------------
__global__ void k_final(const float* __restrict__ hmax,
                        const float* __restrict__ fcw,
                        const float* __restrict__ fcb,
                        float* __restrict__ out)
{
    const int b = threadIdx.x;
    if (b >= B_) return;
    float y0 = fcb[0], y1 = fcb[1];
    for (int m = 0; m < 400; ++m) {
        const int e   = m / 200;
        const int dm  = m % 200;
        const int dir = dm / 100;
        const int j   = dm % 100;
        const float x = hmax[((size_t)((e * 2 + dir) * 64 + b)) * HH + j];
        y0 += fcw[m]       * x;
        y1 += fcw[400 + m] * x;
    }
    const float mx = fmaxf(y0, y1);
    const float e0 = __expf(y0 - mx), e1 = __expf(y1 - mx);
    const float s = e0 + e1;
    out[b * 2]     = e0 / s;
    out[b * 2 + 1] = e1 / s;
}

extern "C" void kernel_launch(void* const* d_in, const int* in_sizes, int n_in,
                              void* d_out, int out_size, void* d_ws, size_t ws_size,
                              hipStream_t stream)
{
    const int*   tok1  = (const int*)d_in[0];
    const int*   tok2  = (const int*)d_in[1];
    const float* emb   = (const float*)d_in[4];
    const float* Wc    = (const float*)d_in[5];
    const float* bc    = (const float*)d_in[6];
    const float* wih_f = (const float*)d_in[7];
    const float* whh_f = (const float*)d_in[8];
    const float* bih_f = (const float*)d_in[9];
    const float* bhh_f = (const float*)d_in[10];
    const float* wih_b = (const float*)d_in[11];
    const float* whh_b = (const float*)d_in[12];
    const float* bih_b = (const float*)d_in[13];
    const float* bhh_b = (const float*)d_in[14];
    const float* fcw   = (const float*)d_in[15];
    const float* fcb   = (const float*)d_in[16];

    char* ws = (char*)d_ws;
    unsigned short* wc_bf   = (unsigned short*)(ws + WC_BF_OFF);
    unsigned short* wih_pad = (unsigned short*)(ws + WIH_BF_OFF);
    unsigned short* whh_pad = (unsigned short*)(ws + WHH_BF_OFF);
    unsigned short* enc_bf  = (unsigned short*)(ws + ENC_BF_OFF);
    float*          hmax    = (float*)(ws + HMAX_OFF);

    k_prep<<<208, 256, 0, stream>>>(Wc, wih_f, wih_b, whh_f, whh_b,
                                    wc_bf, wih_pad, whh_pad);
    k_encode<<<2048, 512, 0, stream>>>(tok1, tok2, emb, wc_bf, bc, enc_bf);
    k_gru<<<64, 256, 0, stream>>>(enc_bf, wih_pad, whh_pad,
                                  bih_f, bih_b, bhh_f, bhh_b, hmax);
    k_final<<<1, 64, 0, stream>>>(hmax, fcw, fcb, (float*)d_out);
}

// Round 13
// 146.814 us; speedup vs baseline: 1.1342x; 1.1342x over previous
//
#include <hip/hip_runtime.h>
#include <math.h>

#define B_      64
#define S_      128
#define KN      16
#define EE      128
#define HH      100
#define NTREE   8192            // B_*S_

typedef __attribute__((ext_vector_type(8))) short   bf8;    // 8 bf16 (4 VGPRs)
typedef __attribute__((ext_vector_type(2))) float   f32x2;
typedef __attribute__((ext_vector_type(4))) float   f32x4;
typedef __attribute__((ext_vector_type(4))) unsigned int u32x4;

// workspace byte offsets (256-aligned)
#define WC_BF_OFF    12800000u    // 128*128*2   = 32,768
#define WIH_BF_OFF   12832768u    // 768*128*2   = 196,608 (padded [dir][g][128j][128k])
#define WHH_BF_OFF   13029376u    // 768*128*2   = 196,608 (padded, zero pads)
#define ENC_BF_OFF   13225984u    // 16384*128*2 = 4,194,304   rows = e*8192 + t*64 + b
#define HMAX_OFF     17420288u    // 25600*4     = 102,400

__constant__ float c_cnt[16] = {16.f,8.f,7.f,4.f,3.f,3.f,3.f,2.f,
                                1.f,1.f,1.f,1.f,1.f,1.f,1.f,1.f};

__device__ __forceinline__ unsigned short f2bf(float f) {
    unsigned int x = __builtin_bit_cast(unsigned int, f);
    x = x + 0x7fffu + ((x >> 16) & 1u);          // RNE
    return (unsigned short)(x >> 16);
}
__device__ __forceinline__ unsigned int pack2(const f32x2& v) {
    return (unsigned int)f2bf(v[0]) | ((unsigned int)f2bf(v[1]) << 16);
}
__device__ __forceinline__ float selq(const f32x4& v, int q) {
    const float a = (q & 1) ? v[1] : v[0];
    const float b = (q & 1) ? v[3] : v[2];
    return (q & 2) ? b : a;
}
// swizzle a 16B-aligned column-byte offset within a 256B row
#define SWZ(row, cb) ((cb) ^ (((row) & 7) << 4))

// ---------------------------------------------------------------------------
// K0: fp32 -> bf16 prep of Wc + wih/whh padded [2][3][128j][128k] (zero pads).
// emb stays fp32 (k_encode gathers directly).
// ---------------------------------------------------------------------------
#define NB 4096      // Wc float4s
#define NC 24576     // wih_pad ushort4s (768*128/4)
#define ND 24576     // whh_pad ushort4s
__global__ __launch_bounds__(256) void k_prep(
    const float* __restrict__ Wc,
    const float* __restrict__ wih_f, const float* __restrict__ wih_b,
    const float* __restrict__ whh_f, const float* __restrict__ whh_b,
    unsigned short* __restrict__ wc_bf,
    unsigned short* __restrict__ wih_pad, unsigned short* __restrict__ whh_pad)
{
    const int i = blockIdx.x * 256 + threadIdx.x;
    if (i < NB) {
        float4 v = ((const float4*)Wc)[i];
        ushort4 o;
        o.x = f2bf(v.x); o.y = f2bf(v.y); o.z = f2bf(v.z); o.w = f2bf(v.w);
        ((ushort4*)wc_bf)[i] = o;
    } else if (i < NB + NC) {
        const int u = i - NB;                       // 0..24575
        const int row = u >> 5, k4 = u & 31;        // row 0..767
        const int dir = row / 384, rem = row % 384, g = rem >> 7, j = rem & 127;
        ushort4 o = {0, 0, 0, 0};
        if (j < 100) {
            const float* w = dir ? wih_b : wih_f;   // [300][128]
            float4 v = ((const float4*)w)[(g * 100 + j) * 32 + k4];
            o.x = f2bf(v.x); o.y = f2bf(v.y); o.z = f2bf(v.z); o.w = f2bf(v.w);
        }
        ((ushort4*)wih_pad)[u] = o;
    } else if (i < NB + NC + ND) {
        const int u = i - NB - NC;
        const int row = u >> 5, k0 = (u & 31) * 4;
        const int dir = row / 384, rem = row % 384, g = rem >> 7, j = rem & 127;
        ushort4 o = {0, 0, 0, 0};
        if (j < 100) {
            const float* w = dir ? whh_b : whh_f;   // [300][100]
            const float* wr = w + (g * 100 + j) * 100;
            unsigned short t[4];
            #pragma unroll
            for (int q = 0; q < 4; ++q)
                t[q] = (k0 + q < 100) ? f2bf(wr[k0 + q]) : (unsigned short)0;
            o.x = t[0]; o.y = t[1]; o.z = t[2]; o.w = t[3];
        }
        ((ushort4*)whh_pad)[u] = o;
    }
}

// ---------------------------------------------------------------------------
// K1: REGISTER tree aggregation, no cross-lane ops. Thread = (tree = tid>>6,
// sd = tid&63: 2-dim segment). Loads 16 float2 (coalesced across wave),
// sums the binary tree in fp32 regs, writes 16 x 4B (2 bf16) to A tile
// (64 lanes x contiguous 256B row -> conflict-free). Then MFMA GEMM with
// B = Wc bf16; epilogue: +cnt*bc, per-tree max, relu.
// ---------------------------------------------------------------------------
__global__ __launch_bounds__(512) void k_encode(
    const int* __restrict__ tok1, const int* __restrict__ tok2,
    const float* __restrict__ emb,
    const unsigned short* __restrict__ wc_bf,
    const float* __restrict__ bc,
    unsigned short* __restrict__ enc_bf)
{
    __shared__ unsigned short A_lds[128 * 128];   // [row][k] swizzled (32KB)
    __shared__ unsigned short B_lds[128 * 128];   // [col][k] swizzled (32KB)
    const int tid = threadIdx.x;
    const int blk = blockIdx.x;
    const int e = blk >> 10;
    const int tree0 = (blk & 1023) * 8;
    const int* __restrict__ tok = e ? tok2 : tok1;

    const int lane = tid & 63;
    const int tr = tid >> 6;         // tree 0..7 (== wave)
    const int sd = tid & 63;         // 2-dim segment: dims [2*sd, 2*sd+1]

    // stage Wc loads early
    u32x4 wcv[4];
    #pragma unroll
    for (int it = 0; it < 4; ++it) {
        const int idx = tid + 512 * it;          // 0..2047
        wcv[it] = *(const u32x4*)(wc_bf + (idx >> 4) * EE + (idx & 15) * 8);
    }

    // tokens (4 x int4 = all 16 nodes of this tree)
    const int4* tkp = (const int4*)(tok + (tree0 + tr) * KN);
    const int4 tkA = tkp[0], tkB = tkp[1], tkC = tkp[2], tkD = tkp[3];

    // gather 16 x float2 (independent loads, coalesced per row)
#define LDE(tk) (*(const f32x2*)(emb + (size_t)(tk) * EE + sd * 2))
    f32x2 a0 = LDE(tkA.x), a1 = LDE(tkA.y), a2  = LDE(tkA.z), a3  = LDE(tkA.w);
    f32x2 a4 = LDE(tkB.x), a5 = LDE(tkB.y), a6  = LDE(tkB.z), a7  = LDE(tkB.w);
    f32x2 a8 = LDE(tkC.x), a9 = LDE(tkC.y), a10 = LDE(tkC.z), a11 = LDE(tkC.w);
    f32x2 a12 = LDE(tkD.x), a13 = LDE(tkD.y), a14 = LDE(tkD.z), a15 = LDE(tkD.w);
#undef LDE

    // bottom-up child-sum (pure VALU)
    a7 += a15;
    a3 += a7  + a8;   a4 += a9  + a10;
    a5 += a11 + a12;  a6 += a13 + a14;
    a1 += a3  + a4;   a2 += a5  + a6;
    a0 += a1  + a2;

    // write to A tile: 4B per node at swizzled chunk
    {
        const int cb = (sd >> 2) << 4;       // 16B chunk byte offset
        const int ib = (sd & 3) * 4;         // byte within chunk
        const int r0 = tr * 16;
#define STA(n, v) *(unsigned int*)((char*)A_lds + (r0 + (n)) * 256 \
                    + (cb ^ (((r0 + (n)) & 7) << 4)) + ib) = pack2(v);
        STA(0, a0)  STA(1, a1)  STA(2, a2)   STA(3, a3)
        STA(4, a4)  STA(5, a5)  STA(6, a6)   STA(7, a7)
        STA(8, a8)  STA(9, a9)  STA(10, a10) STA(11, a11)
        STA(12, a12) STA(13, a13) STA(14, a14) STA(15, a15)
#undef STA
    }
    #pragma unroll
    for (int it = 0; it < 4; ++it) {
        const int idx = tid + 512 * it;
        const int row = idx >> 4, sg = idx & 15;
        *(u32x4*)((char*)B_lds + row * 256 + SWZ(row, sg * 16)) = wcv[it];
    }
    __syncthreads();

    const int wid = tid >> 6;
    const int wr = wid >> 1, wc = wid & 1;
    const int l15 = lane & 15, lg = lane >> 4;

    f32x4 acc[2][4];
    #pragma unroll
    for (int rt = 0; rt < 2; ++rt)
        #pragma unroll
        for (int ct = 0; ct < 4; ++ct) acc[rt][ct] = (f32x4){0.f, 0.f, 0.f, 0.f};

    #pragma unroll
    for (int ks = 0; ks < 4; ++ks) {
        bf8 aF[2], bF[4];
        #pragma unroll
        for (int rt = 0; rt < 2; ++rt) {
            const int row = wr * 32 + rt * 16 + l15;
            aF[rt] = *(const bf8*)((const char*)A_lds + row * 256 + SWZ(row, ks * 64 + lg * 16));
        }
        #pragma unroll
        for (int ct = 0; ct < 4; ++ct) {
            const int col = wc * 64 + ct * 16 + l15;
            bF[ct] = *(const bf8*)((const char*)B_lds + col * 256 + SWZ(col, ks * 64 + lg * 16));
        }
        #pragma unroll
        for (int rt = 0; rt < 2; ++rt)
            #pragma unroll
            for (int ct = 0; ct < 4; ++ct)
                acc[rt][ct] = __builtin_amdgcn_mfma_f32_16x16x32_bf16(aF[rt], bF[ct], acc[rt][ct], 0, 0, 0);
    }

    #pragma unroll
    for (int rt = 0; rt < 2; ++rt) {
        const int ltree = wr * 2 + rt;
        #pragma unroll
        for (int ct = 0; ct < 4; ++ct) {
            const int col = wc * 64 + ct * 16 + l15;
            const float bcv = bc[col];
            f32x4 v = acc[rt][ct];
            float m = -1e30f;
            #pragma unroll
            for (int r = 0; r < 4; ++r)
                m = fmaxf(m, v[r] + c_cnt[lg * 4 + r] * bcv);
            m = fmaxf(m, __shfl_xor(m, 16));
            m = fmaxf(m, __shfl_xor(m, 32));
            m = fmaxf(m, 0.f);
            if (lg == 0) {
                const int gtree = tree0 + ltree;
                const int row = (gtree & 127) * 64 + (gtree >> 7);   // t*64 + b
                enc_bf[((size_t)e * NTREE + row) * EE + col] = f2bf(m);
            }
        }
    }
}

// ---------------------------------------------------------------------------
// K3: LDS-resident GRU scan (R11 structure: 64 blocks x 448 thr, 7 waves)
// + eC/eN one-step-ahead enc prefetch: post-barrier the ih-MFMAs start
// immediately on eC (ready), overlapping the hF ds_read latency.
// Gate split q=l15>>2: 1 gate-unit/lane, scalar gates, 2B h-write.
// ---------------------------------------------------------------------------
__global__ __launch_bounds__(448, 2) void k_gru(
    const unsigned short* __restrict__ enc_bf,
    const unsigned short* __restrict__ wih_pad,
    const unsigned short* __restrict__ whh_pad,
    const float* __restrict__ bih_f, const float* __restrict__ bih_b,
    const float* __restrict__ bhh_f, const float* __restrict__ bhh_b,
    float* __restrict__ hmax_out)
{
    __shared__ unsigned char enc_lds[4 * 128 * 256];  // 128KB [c][t][chunk^(c<<2)]
    __shared__ unsigned char h_lds[2][4 * 256];       // 2KB dbuf, rotated chunks
    const int tid  = threadIdx.x;
    const int blk  = blockIdx.x;        // 64
    const int e    = blk >> 5;
    const int dir  = (blk >> 4) & 1;
    const int b0   = (blk & 15) * 4;
    const int lane = tid & 63;
    const int l15  = lane & 15;
    const int lg   = lane >> 4;
    const int c    = l15 & 3;           // seq column
    const int q    = l15 >> 2;          // owned r-slot (gate split)
    const int jbase = (tid >> 6) * 16;
    const int j_own = jbase + lg * 4 + q;

    for (int u = tid; u < 512; u += 448)
        ((unsigned int*)h_lds)[u] = 0u;

    // stage enc slice into LDS (content chunk = rc ^ (c<<2))
    #pragma unroll
    for (int i = 0; i < 19; ++i) {
        const int s = tid + i * 448;
        if (s < 8192) {
            const int sc = s >> 11, st = (s >> 4) & 127, rc = s & 15;
            const int gch = rc ^ (sc << 2);
            const u32x4 v = *(const u32x4*)(enc_bf
                + ((size_t)e * NTREE + st * 64 + b0 + sc) * EE + gch * 8);
            *(u32x4*)(enc_lds + s * 16) = v;
        }
    }

    // weight A-frags: row j = jbase + l15, k = ks*32 + lg*8
    bf8 aI[3][4], aH[3][4];
    {
        const unsigned short* wiP = wih_pad + (size_t)dir * 3 * 128 * 128;
        const unsigned short* whP = whh_pad + (size_t)dir * 3 * 128 * 128;
        #pragma unroll
        for (int g = 0; g < 3; ++g)
            #pragma unroll
            for (int ks = 0; ks < 4; ++ks) {
                const size_t ro = (size_t)(g * 128 + jbase + l15) * 128 + ks * 32 + lg * 8;
                aI[g][ks] = *(const bf8*)(wiP + ro);
                aH[g][ks] = *(const bf8*)(whP + ro);
            }
    }
    const float* __restrict__ bih = dir ? bih_b : bih_f;
    const float* __restrict__ bhh = dir ? bhh_b : bhh_f;
    f32x4 bR, bZ, bI_, bH_;
    #pragma unroll
    for (int r = 0; r < 4; ++r) {
        const int j = jbase + lg * 4 + r;
        bR[r]  = (j < 100) ? bih[j]       + bhh[j]       : 0.f;
        bZ[r]  = (j < 100) ? bih[100 + j] + bhh[100 + j] : 0.f;
        bI_[r] = (j < 100) ? bih[200 + j] : 0.f;
        bH_[r] = (j < 100) ? bhh[200 + j] : 0.f;
    }

    // constant per-lane LDS offsets
    unsigned int eoff[4], hoff[4];
    #pragma unroll
    for (int ks = 0; ks < 4; ++ks) {
        eoff[ks] = c * 32768 + ((((ks * 4 + lg) ^ (c << 2)) & 15) << 4);
        hoff[ks] = c * 256 + (((ks * 4 + lg + 4 * c) & 15) << 4);
    }
    const unsigned int hw_off = c * 256
        + ((((j_own >> 3) + 4 * c) & 15) << 4) + (j_own & 7) * 2;

    float h_cur = 0.f;
    float hmx   = -1e30f;
    __syncthreads();   // staging + h-zero complete (one-time drain)

    bf8 eC[4], eN[4];
    {
        const int tm = dir ? 127 : 0;
        #pragma unroll
        for (int ks = 0; ks < 4; ++ks)
            eC[ks] = *(const bf8*)(enc_lds + tm * 256 + eoff[ks]);
    }

#define L2E  1.4426950408889634f
#define GRU_STEP(EC, EN, P, S)                                                 \
    {                                                                          \
        bf8 hF[4];                                                             \
        _Pragma("unroll")                                                      \
        for (int ks = 0; ks < 4; ++ks)                                         \
            hF[ks] = *(const bf8*)(h_lds[P] + hoff[ks]);                       \
        f32x4 ar = bR, az = bZ, ai = bI_, ah = bH_;                            \
        _Pragma("unroll")                                                      \
        for (int ks = 0; ks < 4; ++ks) {                                       \
            ar = __builtin_amdgcn_mfma_f32_16x16x32_bf16(aI[0][ks], EC[ks], ar, 0, 0, 0); \
            az = __builtin_amdgcn_mfma_f32_16x16x32_bf16(aI[1][ks], EC[ks], az, 0, 0, 0); \
            ai = __builtin_amdgcn_mfma_f32_16x16x32_bf16(aI[2][ks], EC[ks], ai, 0, 0, 0); \
        }                                                                      \
        if ((S) + 1 < S_) {                                                    \
            const int tmn = dir ? (126 - (S)) : ((S) + 1);                     \
            _Pragma("unroll")                                                  \
            for (int ks = 0; ks < 4; ++ks)                                     \
                EN[ks] = *(const bf8*)(enc_lds + tmn * 256 + eoff[ks]);        \
        }                                                                      \
        _Pragma("unroll")                                                      \
        for (int ks = 0; ks < 4; ++ks) {                                       \
            ar = __builtin_amdgcn_mfma_f32_16x16x32_bf16(aH[0][ks], hF[ks], ar, 0, 0, 0); \
            az = __builtin_amdgcn_mfma_f32_16x16x32_bf16(aH[1][ks], hF[ks], az, 0, 0, 0); \
            ah = __builtin_amdgcn_mfma_f32_16x16x32_bf16(aH[2][ks], hF[ks], ah, 0, 0, 0); \
        }                                                                      \
        const float gr  = selq(ar, q);                                         \
        const float gz  = selq(az, q);                                         \
        const float gi_ = selq(ai, q);                                         \
        const float gh_ = selq(ah, q);                                         \
        const float rg  = __builtin_amdgcn_rcpf(1.f + __builtin_amdgcn_exp2f(-L2E * gr)); \
        const float zg  = __builtin_amdgcn_rcpf(1.f + __builtin_amdgcn_exp2f(-L2E * gz)); \
        const float nx  = gi_ + rg * gh_;                                      \
        const float ng  = 1.f - 2.f * __builtin_amdgcn_rcpf(1.f + __builtin_amdgcn_exp2f((2.f * L2E) * nx)); \
        const float hnew = ng + zg * (h_cur - ng);                             \
        h_cur = hnew;                                                          \
        hmx = fmaxf(hmx, hnew);                                                \
        *(unsigned short*)(h_lds[(P) ^ 1] + hw_off) = f2bf(hnew);              \
        __builtin_amdgcn_sched_barrier(0);                                     \
        asm volatile("s_waitcnt lgkmcnt(0)");                                  \
        __builtin_amdgcn_s_barrier();                                          \
        __builtin_amdgcn_sched_barrier(0);                                     \
    }

    for (int t = 0; t < S_; t += 2) {
        GRU_STEP(eC, eN, 0, t)
        GRU_STEP(eN, eC, 1, t + 1)
    }
#undef GRU_STEP

    if (j_own < 100)
        hmax_out[((size_t)((e * 2 + dir) * 64 + b0 + c)) * HH + j_own] = hmx;
}

// ---------------------------------------------------------------------------
// K4: fc + softmax
// ---------------------------------------------------------------------------
__global__ void k_final(const float* __restrict__ hmax,
                        const float* __restrict__ fcw,
                        const float* __restrict__ fcb,
                        float* __restrict__ out)
{
    const int b = threadIdx.x;
    if (b >= B_) return;
    float y0 = fcb[0], y1 = fcb[1];
    for (int m = 0; m < 400; ++m) {
        const int e   = m / 200;
        const int dm  = m % 200;
        const int dir = dm / 100;
        const int j   = dm % 100;
        const float x = hmax[((size_t)((e * 2 + dir) * 64 + b)) * HH + j];
        y0 += fcw[m]       * x;
        y1 += fcw[400 + m] * x;
    }
    const float mx = fmaxf(y0, y1);
    const float e0 = __expf(y0 - mx), e1 = __expf(y1 - mx);
    const float s = e0 + e1;
    out[b * 2]     = e0 / s;
    out[b * 2 + 1] = e1 / s;
}

extern "C" void kernel_launch(void* const* d_in, const int* in_sizes, int n_in,
                              void* d_out, int out_size, void* d_ws, size_t ws_size,
                              hipStream_t stream)
{
    const int*   tok1  = (const int*)d_in[0];
    const int*   tok2  = (const int*)d_in[1];
    const float* emb   = (const float*)d_in[4];
    const float* Wc    = (const float*)d_in[5];
    const float* bc    = (const float*)d_in[6];
    const float* wih_f = (const float*)d_in[7];
    const float* whh_f = (const float*)d_in[8];
    const float* bih_f = (const float*)d_in[9];
    const float* bhh_f = (const float*)d_in[10];
    const float* wih_b = (const float*)d_in[11];
    const float* whh_b = (const float*)d_in[12];
    const float* bih_b = (const float*)d_in[13];
    const float* bhh_b = (const float*)d_in[14];
    const float* fcw   = (const float*)d_in[15];
    const float* fcb   = (const float*)d_in[16];

    char* ws = (char*)d_ws;
    unsigned short* wc_bf   = (unsigned short*)(ws + WC_BF_OFF);
    unsigned short* wih_pad = (unsigned short*)(ws + WIH_BF_OFF);
    unsigned short* whh_pad = (unsigned short*)(ws + WHH_BF_OFF);
    unsigned short* enc_bf  = (unsigned short*)(ws + ENC_BF_OFF);
    float*          hmax    = (float*)(ws + HMAX_OFF);

    k_prep<<<208, 256, 0, stream>>>(Wc, wih_f, wih_b, whh_f, whh_b,
                                    wc_bf, wih_pad, whh_pad);
    k_encode<<<2048, 512, 0, stream>>>(tok1, tok2, emb, wc_bf, bc, enc_bf);
    k_gru<<<64, 448, 0, stream>>>(enc_bf, wih_pad, whh_pad,
                                  bih_f, bih_b, bhh_f, bhh_b, hmax);
    k_final<<<1, 64, 0, stream>>>(hmax, fcw, fcb, (float*)d_out);
}

// Round 14
// 125.440 us; speedup vs baseline: 1.3274x; 1.1704x over previous
//
#include <hip/hip_runtime.h>
#include <math.h>

#define B_      64
#define S_      128
#define KN      16
#define EE      128
#define HH      100
#define NTREE   8192            // B_*S_

typedef __attribute__((ext_vector_type(8))) short   bf8;    // 8 bf16 (4 VGPRs)
typedef __attribute__((ext_vector_type(2))) float   f32x2;
typedef __attribute__((ext_vector_type(4))) float   f32x4;
typedef __attribute__((ext_vector_type(4))) unsigned int u32x4;

// workspace byte offsets (256-aligned)
#define WC_BF_OFF    12800000u    // 128*128*2   = 32,768
#define WIH_BF_OFF   12832768u    // 768*128*2   = 196,608 (padded [dir][g][128j][128k])
#define WHH_BF_OFF   13029376u    // 768*128*2   = 196,608 (padded, zero pads)
#define ENC_BF_OFF   13225984u    // 16384*128*2 = 4,194,304   rows = e*8192 + t*64 + b
#define HMAX_OFF     17420288u    // 25600*4     = 102,400

__constant__ float c_cnt[16] = {16.f,8.f,7.f,4.f,3.f,3.f,3.f,2.f,
                                1.f,1.f,1.f,1.f,1.f,1.f,1.f,1.f};

__device__ __forceinline__ unsigned short f2bf(float f) {
    unsigned int x = __builtin_bit_cast(unsigned int, f);
    x = x + 0x7fffu + ((x >> 16) & 1u);          // RNE
    return (unsigned short)(x >> 16);
}
__device__ __forceinline__ unsigned int pack2(const f32x2& v) {
    return (unsigned int)f2bf(v[0]) | ((unsigned int)f2bf(v[1]) << 16);
}
__device__ __forceinline__ float selq(const f32x4& v, int q) {
    const float a = (q & 1) ? v[1] : v[0];
    const float b = (q & 1) ? v[3] : v[2];
    return (q & 2) ? b : a;
}
// swizzle a 16B-aligned column-byte offset within a 256B row
#define SWZ(row, cb) ((cb) ^ (((row) & 7) << 4))

// ---------------------------------------------------------------------------
// K0: fp32 -> bf16 prep of Wc + wih/whh padded [2][3][128j][128k] (zero pads).
// emb stays fp32 (k_encode gathers directly).
// ---------------------------------------------------------------------------
#define NB 4096      // Wc float4s
#define NC 24576     // wih_pad ushort4s (768*128/4)
#define ND 24576     // whh_pad ushort4s
__global__ __launch_bounds__(256) void k_prep(
    const float* __restrict__ Wc,
    const float* __restrict__ wih_f, const float* __restrict__ wih_b,
    const float* __restrict__ whh_f, const float* __restrict__ whh_b,
    unsigned short* __restrict__ wc_bf,
    unsigned short* __restrict__ wih_pad, unsigned short* __restrict__ whh_pad)
{
    const int i = blockIdx.x * 256 + threadIdx.x;
    if (i < NB) {
        float4 v = ((const float4*)Wc)[i];
        ushort4 o;
        o.x = f2bf(v.x); o.y = f2bf(v.y); o.z = f2bf(v.z); o.w = f2bf(v.w);
        ((ushort4*)wc_bf)[i] = o;
    } else if (i < NB + NC) {
        const int u = i - NB;                       // 0..24575
        const int row = u >> 5, k4 = u & 31;        // row 0..767
        const int dir = row / 384, rem = row % 384, g = rem >> 7, j = rem & 127;
        ushort4 o = {0, 0, 0, 0};
        if (j < 100) {
            const float* w = dir ? wih_b : wih_f;   // [300][128]
            float4 v = ((const float4*)w)[(g * 100 + j) * 32 + k4];
            o.x = f2bf(v.x); o.y = f2bf(v.y); o.z = f2bf(v.z); o.w = f2bf(v.w);
        }
        ((ushort4*)wih_pad)[u] = o;
    } else if (i < NB + NC + ND) {
        const int u = i - NB - NC;
        const int row = u >> 5, k0 = (u & 31) * 4;
        const int dir = row / 384, rem = row % 384, g = rem >> 7, j = rem & 127;
        ushort4 o = {0, 0, 0, 0};
        if (j < 100) {
            const float* w = dir ? whh_b : whh_f;   // [300][100]
            const float* wr = w + (g * 100 + j) * 100;
            unsigned short t[4];
            #pragma unroll
            for (int q = 0; q < 4; ++q)
                t[q] = (k0 + q < 100) ? f2bf(wr[k0 + q]) : (unsigned short)0;
            o.x = t[0]; o.y = t[1]; o.z = t[2]; o.w = t[3];
        }
        ((ushort4*)whh_pad)[u] = o;
    }
}

// ---------------------------------------------------------------------------
// K1: REGISTER tree aggregation, no cross-lane ops. (unchanged from R13)
// ---------------------------------------------------------------------------
__global__ __launch_bounds__(512) void k_encode(
    const int* __restrict__ tok1, const int* __restrict__ tok2,
    const float* __restrict__ emb,
    const unsigned short* __restrict__ wc_bf,
    const float* __restrict__ bc,
    unsigned short* __restrict__ enc_bf)
{
    __shared__ unsigned short A_lds[128 * 128];   // [row][k] swizzled (32KB)
    __shared__ unsigned short B_lds[128 * 128];   // [col][k] swizzled (32KB)
    const int tid = threadIdx.x;
    const int blk = blockIdx.x;
    const int e = blk >> 10;
    const int tree0 = (blk & 1023) * 8;
    const int* __restrict__ tok = e ? tok2 : tok1;

    const int lane = tid & 63;
    const int tr = tid >> 6;         // tree 0..7 (== wave)
    const int sd = tid & 63;         // 2-dim segment: dims [2*sd, 2*sd+1]

    // stage Wc loads early
    u32x4 wcv[4];
    #pragma unroll
    for (int it = 0; it < 4; ++it) {
        const int idx = tid + 512 * it;          // 0..2047
        wcv[it] = *(const u32x4*)(wc_bf + (idx >> 4) * EE + (idx & 15) * 8);
    }

    // tokens (4 x int4 = all 16 nodes of this tree)
    const int4* tkp = (const int4*)(tok + (tree0 + tr) * KN);
    const int4 tkA = tkp[0], tkB = tkp[1], tkC = tkp[2], tkD = tkp[3];

    // gather 16 x float2 (independent loads, coalesced per row)
#define LDE(tk) (*(const f32x2*)(emb + (size_t)(tk) * EE + sd * 2))
    f32x2 a0 = LDE(tkA.x), a1 = LDE(tkA.y), a2  = LDE(tkA.z), a3  = LDE(tkA.w);
    f32x2 a4 = LDE(tkB.x), a5 = LDE(tkB.y), a6  = LDE(tkB.z), a7  = LDE(tkB.w);
    f32x2 a8 = LDE(tkC.x), a9 = LDE(tkC.y), a10 = LDE(tkC.z), a11 = LDE(tkC.w);
    f32x2 a12 = LDE(tkD.x), a13 = LDE(tkD.y), a14 = LDE(tkD.z), a15 = LDE(tkD.w);
#undef LDE

    // bottom-up child-sum (pure VALU)
    a7 += a15;
    a3 += a7  + a8;   a4 += a9  + a10;
    a5 += a11 + a12;  a6 += a13 + a14;
    a1 += a3  + a4;   a2 += a5  + a6;
    a0 += a1  + a2;

    // write to A tile: 4B per node at swizzled chunk
    {
        const int cb = (sd >> 2) << 4;       // 16B chunk byte offset
        const int ib = (sd & 3) * 4;         // byte within chunk
        const int r0 = tr * 16;
#define STA(n, v) *(unsigned int*)((char*)A_lds + (r0 + (n)) * 256 \
                    + (cb ^ (((r0 + (n)) & 7) << 4)) + ib) = pack2(v);
        STA(0, a0)  STA(1, a1)  STA(2, a2)   STA(3, a3)
        STA(4, a4)  STA(5, a5)  STA(6, a6)   STA(7, a7)
        STA(8, a8)  STA(9, a9)  STA(10, a10) STA(11, a11)
        STA(12, a12) STA(13, a13) STA(14, a14) STA(15, a15)
#undef STA
    }
    #pragma unroll
    for (int it = 0; it < 4; ++it) {
        const int idx = tid + 512 * it;
        const int row = idx >> 4, sg = idx & 15;
        *(u32x4*)((char*)B_lds + row * 256 + SWZ(row, sg * 16)) = wcv[it];
    }
    __syncthreads();

    const int wid = tid >> 6;
    const int wr = wid >> 1, wc = wid & 1;
    const int l15 = lane & 15, lg = lane >> 4;

    f32x4 acc[2][4];
    #pragma unroll
    for (int rt = 0; rt < 2; ++rt)
        #pragma unroll
        for (int ct = 0; ct < 4; ++ct) acc[rt][ct] = (f32x4){0.f, 0.f, 0.f, 0.f};

    #pragma unroll
    for (int ks = 0; ks < 4; ++ks) {
        bf8 aF[2], bF[4];
        #pragma unroll
        for (int rt = 0; rt < 2; ++rt) {
            const int row = wr * 32 + rt * 16 + l15;
            aF[rt] = *(const bf8*)((const char*)A_lds + row * 256 + SWZ(row, ks * 64 + lg * 16));
        }
        #pragma unroll
        for (int ct = 0; ct < 4; ++ct) {
            const int col = wc * 64 + ct * 16 + l15;
            bF[ct] = *(const bf8*)((const char*)B_lds + col * 256 + SWZ(col, ks * 64 + lg * 16));
        }
        #pragma unroll
        for (int rt = 0; rt < 2; ++rt)
            #pragma unroll
            for (int ct = 0; ct < 4; ++ct)
                acc[rt][ct] = __builtin_amdgcn_mfma_f32_16x16x32_bf16(aF[rt], bF[ct], acc[rt][ct], 0, 0, 0);
    }

    #pragma unroll
    for (int rt = 0; rt < 2; ++rt) {
        const int ltree = wr * 2 + rt;
        #pragma unroll
        for (int ct = 0; ct < 4; ++ct) {
            const int col = wc * 64 + ct * 16 + l15;
            const float bcv = bc[col];
            f32x4 v = acc[rt][ct];
            float m = -1e30f;
            #pragma unroll
            for (int r = 0; r < 4; ++r)
                m = fmaxf(m, v[r] + c_cnt[lg * 4 + r] * bcv);
            m = fmaxf(m, __shfl_xor(m, 16));
            m = fmaxf(m, __shfl_xor(m, 32));
            m = fmaxf(m, 0.f);
            if (lg == 0) {
                const int gtree = tree0 + ltree;
                const int row = (gtree & 127) * 64 + (gtree >> 7);   // t*64 + b
                enc_bf[((size_t)e * NTREE + row) * EE + col] = f2bf(m);
            }
        }
    }
}

// ---------------------------------------------------------------------------
// K3: LDS-resident GRU scan (unchanged from R13: 64 blocks x 448 thr,
// 7 waves, eC/eN one-step-ahead enc prefetch, gate split).
// ---------------------------------------------------------------------------
__global__ __launch_bounds__(448, 2) void k_gru(
    const unsigned short* __restrict__ enc_bf,
    const unsigned short* __restrict__ wih_pad,
    const unsigned short* __restrict__ whh_pad,
    const float* __restrict__ bih_f, const float* __restrict__ bih_b,
    const float* __restrict__ bhh_f, const float* __restrict__ bhh_b,
    float* __restrict__ hmax_out)
{
    __shared__ unsigned char enc_lds[4 * 128 * 256];  // 128KB [c][t][chunk^(c<<2)]
    __shared__ unsigned char h_lds[2][4 * 256];       // 2KB dbuf, rotated chunks
    const int tid  = threadIdx.x;
    const int blk  = blockIdx.x;        // 64
    const int e    = blk >> 5;
    const int dir  = (blk >> 4) & 1;
    const int b0   = (blk & 15) * 4;
    const int lane = tid & 63;
    const int l15  = lane & 15;
    const int lg   = lane >> 4;
    const int c    = l15 & 3;           // seq column
    const int q    = l15 >> 2;          // owned r-slot (gate split)
    const int jbase = (tid >> 6) * 16;
    const int j_own = jbase + lg * 4 + q;

    for (int u = tid; u < 512; u += 448)
        ((unsigned int*)h_lds)[u] = 0u;

    // stage enc slice into LDS (content chunk = rc ^ (c<<2))
    #pragma unroll
    for (int i = 0; i < 19; ++i) {
        const int s = tid + i * 448;
        if (s < 8192) {
            const int sc = s >> 11, st = (s >> 4) & 127, rc = s & 15;
            const int gch = rc ^ (sc << 2);
            const u32x4 v = *(const u32x4*)(enc_bf
                + ((size_t)e * NTREE + st * 64 + b0 + sc) * EE + gch * 8);
            *(u32x4*)(enc_lds + s * 16) = v;
        }
    }

    // weight A-frags: row j = jbase + l15, k = ks*32 + lg*8
    bf8 aI[3][4], aH[3][4];
    {
        const unsigned short* wiP = wih_pad + (size_t)dir * 3 * 128 * 128;
        const unsigned short* whP = whh_pad + (size_t)dir * 3 * 128 * 128;
        #pragma unroll
        for (int g = 0; g < 3; ++g)
            #pragma unroll
            for (int ks = 0; ks < 4; ++ks) {
                const size_t ro = (size_t)(g * 128 + jbase + l15) * 128 + ks * 32 + lg * 8;
                aI[g][ks] = *(const bf8*)(wiP + ro);
                aH[g][ks] = *(const bf8*)(whP + ro);
            }
    }
    const float* __restrict__ bih = dir ? bih_b : bih_f;
    const float* __restrict__ bhh = dir ? bhh_b : bhh_f;
    f32x4 bR, bZ, bI_, bH_;
    #pragma unroll
    for (int r = 0; r < 4; ++r) {
        const int j = jbase + lg * 4 + r;
        bR[r]  = (j < 100) ? bih[j]       + bhh[j]       : 0.f;
        bZ[r]  = (j < 100) ? bih[100 + j] + bhh[100 + j] : 0.f;
        bI_[r] = (j < 100) ? bih[200 + j] : 0.f;
        bH_[r] = (j < 100) ? bhh[200 + j] : 0.f;
    }

    // constant per-lane LDS offsets
    unsigned int eoff[4], hoff[4];
    #pragma unroll
    for (int ks = 0; ks < 4; ++ks) {
        eoff[ks] = c * 32768 + ((((ks * 4 + lg) ^ (c << 2)) & 15) << 4);
        hoff[ks] = c * 256 + (((ks * 4 + lg + 4 * c) & 15) << 4);
    }
    const unsigned int hw_off = c * 256
        + ((((j_own >> 3) + 4 * c) & 15) << 4) + (j_own & 7) * 2;

    float h_cur = 0.f;
    float hmx   = -1e30f;
    __syncthreads();   // staging + h-zero complete (one-time drain)

    bf8 eC[4], eN[4];
    {
        const int tm = dir ? 127 : 0;
        #pragma unroll
        for (int ks = 0; ks < 4; ++ks)
            eC[ks] = *(const bf8*)(enc_lds + tm * 256 + eoff[ks]);
    }

#define L2E  1.4426950408889634f
#define GRU_STEP(EC, EN, P, S)                                                 \
    {                                                                          \
        bf8 hF[4];                                                             \
        _Pragma("unroll")                                                      \
        for (int ks = 0; ks < 4; ++ks)                                         \
            hF[ks] = *(const bf8*)(h_lds[P] + hoff[ks]);                       \
        f32x4 ar = bR, az = bZ, ai = bI_, ah = bH_;                            \
        _Pragma("unroll")                                                      \
        for (int ks = 0; ks < 4; ++ks) {                                       \
            ar = __builtin_amdgcn_mfma_f32_16x16x32_bf16(aI[0][ks], EC[ks], ar, 0, 0, 0); \
            az = __builtin_amdgcn_mfma_f32_16x16x32_bf16(aI[1][ks], EC[ks], az, 0, 0, 0); \
            ai = __builtin_amdgcn_mfma_f32_16x16x32_bf16(aI[2][ks], EC[ks], ai, 0, 0, 0); \
        }                                                                      \
        if ((S) + 1 < S_) {                                                    \
            const int tmn = dir ? (126 - (S)) : ((S) + 1);                     \
            _Pragma("unroll")                                                  \
            for (int ks = 0; ks < 4; ++ks)                                     \
                EN[ks] = *(const bf8*)(enc_lds + tmn * 256 + eoff[ks]);        \
        }                                                                      \
        _Pragma("unroll")                                                      \
        for (int ks = 0; ks < 4; ++ks) {                                       \
            ar = __builtin_amdgcn_mfma_f32_16x16x32_bf16(aH[0][ks], hF[ks], ar, 0, 0, 0); \
            az = __builtin_amdgcn_mfma_f32_16x16x32_bf16(aH[1][ks], hF[ks], az, 0, 0, 0); \
            ah = __builtin_amdgcn_mfma_f32_16x16x32_bf16(aH[2][ks], hF[ks], ah, 0, 0, 0); \
        }                                                                      \
        const float gr  = selq(ar, q);                                         \
        const float gz  = selq(az, q);                                         \
        const float gi_ = selq(ai, q);                                         \
        const float gh_ = selq(ah, q);                                         \
        const float rg  = __builtin_amdgcn_rcpf(1.f + __builtin_amdgcn_exp2f(-L2E * gr)); \
        const float zg  = __builtin_amdgcn_rcpf(1.f + __builtin_amdgcn_exp2f(-L2E * gz)); \
        const float nx  = gi_ + rg * gh_;                                      \
        const float ng  = 1.f - 2.f * __builtin_amdgcn_rcpf(1.f + __builtin_amdgcn_exp2f((2.f * L2E) * nx)); \
        const float hnew = ng + zg * (h_cur - ng);                             \
        h_cur = hnew;                                                          \
        hmx = fmaxf(hmx, hnew);                                                \
        *(unsigned short*)(h_lds[(P) ^ 1] + hw_off) = f2bf(hnew);              \
        __builtin_amdgcn_sched_barrier(0);                                     \
        asm volatile("s_waitcnt lgkmcnt(0)");                                  \
        __builtin_amdgcn_s_barrier();                                          \
        __builtin_amdgcn_sched_barrier(0);                                     \
    }

    for (int t = 0; t < S_; t += 2) {
        GRU_STEP(eC, eN, 0, t)
        GRU_STEP(eN, eC, 1, t + 1)
    }
#undef GRU_STEP

    if (j_own < 100)
        hmax_out[((size_t)((e * 2 + dir) * 64 + b0 + c)) * HH + j_own] = hmx;
}

// ---------------------------------------------------------------------------
// K4: fc + softmax — PARALLEL. 512 threads: b = tid>>3, part = tid&7.
// Each part sums 50 of the 400 terms; 3-level shfl reduce within the
// 8-lane group; part 0 does softmax + writes.
// ---------------------------------------------------------------------------
__global__ __launch_bounds__(512) void k_final(
    const float* __restrict__ hmax,
    const float* __restrict__ fcw,
    const float* __restrict__ fcb,
    float* __restrict__ out)
{
    const int tid  = threadIdx.x;
    const int b    = tid >> 3;
    const int part = tid & 7;
    float y0 = 0.f, y1 = 0.f;
    #pragma unroll 2
    for (int i = 0; i < 50; ++i) {
        const int m   = part * 50 + i;
        const int e   = m / 200;
        const int dm  = m % 200;
        const int dir = dm / 100;
        const int j   = dm % 100;
        const float x = hmax[((size_t)((e * 2 + dir) * 64 + b)) * HH + j];
        y0 += fcw[m]       * x;
        y1 += fcw[400 + m] * x;
    }
    #pragma unroll
    for (int m = 1; m < 8; m <<= 1) {
        y0 += __shfl_xor(y0, m);
        y1 += __shfl_xor(y1, m);
    }
    if (part == 0) {
        y0 += fcb[0]; y1 += fcb[1];
        const float mx = fmaxf(y0, y1);
        const float e0 = __expf(y0 - mx), e1 = __expf(y1 - mx);
        const float s = e0 + e1;
        out[b * 2]     = e0 / s;
        out[b * 2 + 1] = e1 / s;
    }
}

extern "C" void kernel_launch(void* const* d_in, const int* in_sizes, int n_in,
                              void* d_out, int out_size, void* d_ws, size_t ws_size,
                              hipStream_t stream)
{
    const int*   tok1  = (const int*)d_in[0];
    const int*   tok2  = (const int*)d_in[1];
    const float* emb   = (const float*)d_in[4];
    const float* Wc    = (const float*)d_in[5];
    const float* bc    = (const float*)d_in[6];
    const float* wih_f = (const float*)d_in[7];
    const float* whh_f = (const float*)d_in[8];
    const float* bih_f = (const float*)d_in[9];
    const float* bhh_f = (const float*)d_in[10];
    const float* wih_b = (const float*)d_in[11];
    const float* whh_b = (const float*)d_in[12];
    const float* bih_b = (const float*)d_in[13];
    const float* bhh_b = (const float*)d_in[14];
    const float* fcw   = (const float*)d_in[15];
    const float* fcb   = (const float*)d_in[16];

    char* ws = (char*)d_ws;
    unsigned short* wc_bf   = (unsigned short*)(ws + WC_BF_OFF);
    unsigned short* wih_pad = (unsigned short*)(ws + WIH_BF_OFF);
    unsigned short* whh_pad = (unsigned short*)(ws + WHH_BF_OFF);
    unsigned short* enc_bf  = (unsigned short*)(ws + ENC_BF_OFF);
    float*          hmax    = (float*)(ws + HMAX_OFF);

    k_prep<<<208, 256, 0, stream>>>(Wc, wih_f, wih_b, whh_f, whh_b,
                                    wc_bf, wih_pad, whh_pad);
    k_encode<<<2048, 512, 0, stream>>>(tok1, tok2, emb, wc_bf, bc, enc_bf);
    k_gru<<<64, 448, 0, stream>>>(enc_bf, wih_pad, whh_pad,
                                  bih_f, bih_b, bhh_f, bhh_b, hmax);
    k_final<<<1, 512, 0, stream>>>(hmax, fcw, fcb, (float*)d_out);
}

// Round 15
// 124.842 us; speedup vs baseline: 1.3338x; 1.0048x over previous
//
#include <hip/hip_runtime.h>
#include <math.h>

#define B_      64
#define S_      128
#define KN      16
#define EE      128
#define HH      100
#define NTREE   8192            // B_*S_

typedef __attribute__((ext_vector_type(8))) short   bf8;    // 8 bf16 (4 VGPRs)
typedef __attribute__((ext_vector_type(2))) float   f32x2;
typedef __attribute__((ext_vector_type(4))) float   f32x4;
typedef __attribute__((ext_vector_type(4))) unsigned int u32x4;

// workspace byte offsets (256-aligned)
#define EMB_BF_OFF   0u           // 50000*128*2 = 12,800,000
#define WC_BF_OFF    12800000u    // 128*128*2   = 32,768
#define WIH_BF_OFF   12832768u    // 768*128*2   = 196,608 (padded [dir][g][128j][128k])
#define WHH_BF_OFF   13029376u    // 768*128*2   = 196,608 (padded, zero pads)
#define ENC_BF_OFF   13225984u    // 16384*128*2 = 4,194,304   rows = e*8192 + t*64 + b
#define HMAX_OFF     17420288u    // 25600*4     = 102,400

__constant__ float c_cnt[16] = {16.f,8.f,7.f,4.f,3.f,3.f,3.f,2.f,
                                1.f,1.f,1.f,1.f,1.f,1.f,1.f,1.f};

__device__ __forceinline__ float bf2f(unsigned short u) {
    unsigned int x = ((unsigned int)u) << 16;
    return __builtin_bit_cast(float, x);
}
__device__ __forceinline__ unsigned short f2bf(float f) {
    unsigned int x = __builtin_bit_cast(unsigned int, f);
    x = x + 0x7fffu + ((x >> 16) & 1u);          // RNE
    return (unsigned short)(x >> 16);
}
__device__ __forceinline__ f32x2 up2(unsigned int u) {
    f32x2 v;
    v[0] = bf2f((unsigned short)(u & 0xffffu));
    v[1] = bf2f((unsigned short)(u >> 16));
    return v;
}
__device__ __forceinline__ unsigned int pack2(const f32x2& v) {
    return (unsigned int)f2bf(v[0]) | ((unsigned int)f2bf(v[1]) << 16);
}
__device__ __forceinline__ float selq(const f32x4& v, int q) {
    const float a = (q & 1) ? v[1] : v[0];
    const float b = (q & 1) ? v[3] : v[2];
    return (q & 2) ? b : a;
}
// swizzle a 16B-aligned column-byte offset within a 256B row
#define SWZ(row, cb) ((cb) ^ (((row) & 7) << 4))

// ---------------------------------------------------------------------------
// K0: fp32 -> bf16 prep: emb + Wc + wih/whh padded [2][3][128j][128k].
// ---------------------------------------------------------------------------
#define NA 1600000   // emb float4s
#define NB 4096      // Wc float4s
#define NC 24576     // wih_pad ushort4s (768*128/4)
#define ND 24576     // whh_pad ushort4s
__global__ __launch_bounds__(256) void k_prep(
    const float* __restrict__ emb, const float* __restrict__ Wc,
    const float* __restrict__ wih_f, const float* __restrict__ wih_b,
    const float* __restrict__ whh_f, const float* __restrict__ whh_b,
    unsigned short* __restrict__ emb_bf, unsigned short* __restrict__ wc_bf,
    unsigned short* __restrict__ wih_pad, unsigned short* __restrict__ whh_pad)
{
    const int i = blockIdx.x * 256 + threadIdx.x;
    if (i < NA + NB) {
        const float* src = (i < NA) ? emb : Wc;
        unsigned short* dst = (i < NA) ? emb_bf : wc_bf;
        const int j = (i < NA) ? i : i - NA;
        float4 v = ((const float4*)src)[j];
        ushort4 o;
        o.x = f2bf(v.x); o.y = f2bf(v.y); o.z = f2bf(v.z); o.w = f2bf(v.w);
        ((ushort4*)dst)[j] = o;
    } else if (i < NA + NB + NC) {
        const int u = i - NA - NB;                  // 0..24575
        const int row = u >> 5, k4 = u & 31;        // row 0..767
        const int dir = row / 384, rem = row % 384, g = rem >> 7, j = rem & 127;
        ushort4 o = {0, 0, 0, 0};
        if (j < 100) {
            const float* w = dir ? wih_b : wih_f;   // [300][128]
            float4 v = ((const float4*)w)[(g * 100 + j) * 32 + k4];
            o.x = f2bf(v.x); o.y = f2bf(v.y); o.z = f2bf(v.z); o.w = f2bf(v.w);
        }
        ((ushort4*)wih_pad)[u] = o;
    } else if (i < NA + NB + NC + ND) {
        const int u = i - NA - NB - NC;
        const int row = u >> 5, k0 = (u & 31) * 4;
        const int dir = row / 384, rem = row % 384, g = rem >> 7, j = rem & 127;
        ushort4 o = {0, 0, 0, 0};
        if (j < 100) {
            const float* w = dir ? whh_b : whh_f;   // [300][100]
            const float* wr = w + (g * 100 + j) * 100;
            unsigned short t[4];
            #pragma unroll
            for (int q = 0; q < 4; ++q)
                t[q] = (k0 + q < 100) ? f2bf(wr[k0 + q]) : (unsigned short)0;
            o.x = t[0]; o.y = t[1]; o.z = t[2]; o.w = t[3];
        }
        ((ushort4*)whh_pad)[u] = o;
    }
}

// ---------------------------------------------------------------------------
// K1: REGISTER tree aggregation (R13 structure), bf16 emb gather (4B/node,
// one full 256B row per wave access — coalesced, half the R13 traffic).
// ---------------------------------------------------------------------------
__global__ __launch_bounds__(512) void k_encode(
    const int* __restrict__ tok1, const int* __restrict__ tok2,
    const unsigned short* __restrict__ emb_bf,
    const unsigned short* __restrict__ wc_bf,
    const float* __restrict__ bc,
    unsigned short* __restrict__ enc_bf)
{
    __shared__ unsigned short A_lds[128 * 128];   // [row][k] swizzled (32KB)
    __shared__ unsigned short B_lds[128 * 128];   // [col][k] swizzled (32KB)
    const int tid = threadIdx.x;
    const int blk = blockIdx.x;
    const int e = blk >> 10;
    const int tree0 = (blk & 1023) * 8;
    const int* __restrict__ tok = e ? tok2 : tok1;

    const int lane = tid & 63;
    const int tr = tid >> 6;         // tree 0..7 (== wave)
    const int sd = tid & 63;         // 2-dim segment: dims [2*sd, 2*sd+1]

    // stage Wc loads early
    u32x4 wcv[4];
    #pragma unroll
    for (int it = 0; it < 4; ++it) {
        const int idx = tid + 512 * it;          // 0..2047
        wcv[it] = *(const u32x4*)(wc_bf + (idx >> 4) * EE + (idx & 15) * 8);
    }

    // tokens (4 x int4 = all 16 nodes of this tree)
    const int4* tkp = (const int4*)(tok + (tree0 + tr) * KN);
    const int4 tkA = tkp[0], tkB = tkp[1], tkC = tkp[2], tkD = tkp[3];

    // gather 16 x u32 (2 bf16 dims each; 64 lanes x 4B = full row, coalesced)
#define LDE(tk) up2(*(const unsigned int*)(emb_bf + (size_t)(tk) * EE + sd * 2))
    f32x2 a0 = LDE(tkA.x), a1 = LDE(tkA.y), a2  = LDE(tkA.z), a3  = LDE(tkA.w);
    f32x2 a4 = LDE(tkB.x), a5 = LDE(tkB.y), a6  = LDE(tkB.z), a7  = LDE(tkB.w);
    f32x2 a8 = LDE(tkC.x), a9 = LDE(tkC.y), a10 = LDE(tkC.z), a11 = LDE(tkC.w);
    f32x2 a12 = LDE(tkD.x), a13 = LDE(tkD.y), a14 = LDE(tkD.z), a15 = LDE(tkD.w);
#undef LDE

    // bottom-up child-sum (pure VALU)
    a7 += a15;
    a3 += a7  + a8;   a4 += a9  + a10;
    a5 += a11 + a12;  a6 += a13 + a14;
    a1 += a3  + a4;   a2 += a5  + a6;
    a0 += a1  + a2;

    // write to A tile: 4B per node at swizzled chunk
    {
        const int cb = (sd >> 2) << 4;       // 16B chunk byte offset
        const int ib = (sd & 3) * 4;         // byte within chunk
        const int r0 = tr * 16;
#define STA(n, v) *(unsigned int*)((char*)A_lds + (r0 + (n)) * 256 \
                    + (cb ^ (((r0 + (n)) & 7) << 4)) + ib) = pack2(v);
        STA(0, a0)  STA(1, a1)  STA(2, a2)   STA(3, a3)
        STA(4, a4)  STA(5, a5)  STA(6, a6)   STA(7, a7)
        STA(8, a8)  STA(9, a9)  STA(10, a10) STA(11, a11)
        STA(12, a12) STA(13, a13) STA(14, a14) STA(15, a15)
#undef STA
    }
    #pragma unroll
    for (int it = 0; it < 4; ++it) {
        const int idx = tid + 512 * it;
        const int row = idx >> 4, sg = idx & 15;
        *(u32x4*)((char*)B_lds + row * 256 + SWZ(row, sg * 16)) = wcv[it];
    }
    __syncthreads();

    const int wid = tid >> 6;
    const int wr = wid >> 1, wc = wid & 1;
    const int l15 = lane & 15, lg = lane >> 4;

    f32x4 acc[2][4];
    #pragma unroll
    for (int rt = 0; rt < 2; ++rt)
        #pragma unroll
        for (int ct = 0; ct < 4; ++ct) acc[rt][ct] = (f32x4){0.f, 0.f, 0.f, 0.f};

    #pragma unroll
    for (int ks = 0; ks < 4; ++ks) {
        bf8 aF[2], bF[4];
        #pragma unroll
        for (int rt = 0; rt < 2; ++rt) {
            const int row = wr * 32 + rt * 16 + l15;
            aF[rt] = *(const bf8*)((const char*)A_lds + row * 256 + SWZ(row, ks * 64 + lg * 16));
        }
        #pragma unroll
        for (int ct = 0; ct < 4; ++ct) {
            const int col = wc * 64 + ct * 16 + l15;
            bF[ct] = *(const bf8*)((const char*)B_lds + col * 256 + SWZ(col, ks * 64 + lg * 16));
        }
        #pragma unroll
        for (int rt = 0; rt < 2; ++rt)
            #pragma unroll
            for (int ct = 0; ct < 4; ++ct)
                acc[rt][ct] = __builtin_amdgcn_mfma_f32_16x16x32_bf16(aF[rt], bF[ct], acc[rt][ct], 0, 0, 0);
    }

    #pragma unroll
    for (int rt = 0; rt < 2; ++rt) {
        const int ltree = wr * 2 + rt;
        #pragma unroll
        for (int ct = 0; ct < 4; ++ct) {
            const int col = wc * 64 + ct * 16 + l15;
            const float bcv = bc[col];
            f32x4 v = acc[rt][ct];
            float m = -1e30f;
            #pragma unroll
            for (int r = 0; r < 4; ++r)
                m = fmaxf(m, v[r] + c_cnt[lg * 4 + r] * bcv);
            m = fmaxf(m, __shfl_xor(m, 16));
            m = fmaxf(m, __shfl_xor(m, 32));
            m = fmaxf(m, 0.f);
            if (lg == 0) {
                const int gtree = tree0 + ltree;
                const int row = (gtree & 127) * 64 + (gtree >> 7);   // t*64 + b
                enc_bf[((size_t)e * NTREE + row) * EE + col] = f2bf(m);
            }
        }
    }
}

// ---------------------------------------------------------------------------
// K3: LDS-resident GRU scan (unchanged from R13: 64 blocks x 448 thr,
// 7 waves, eC/eN one-step-ahead enc prefetch, gate split).
// ---------------------------------------------------------------------------
__global__ __launch_bounds__(448, 2) void k_gru(
    const unsigned short* __restrict__ enc_bf,
    const unsigned short* __restrict__ wih_pad,
    const unsigned short* __restrict__ whh_pad,
    const float* __restrict__ bih_f, const float* __restrict__ bih_b,
    const float* __restrict__ bhh_f, const float* __restrict__ bhh_b,
    float* __restrict__ hmax_out)
{
    __shared__ unsigned char enc_lds[4 * 128 * 256];  // 128KB [c][t][chunk^(c<<2)]
    __shared__ unsigned char h_lds[2][4 * 256];       // 2KB dbuf, rotated chunks
    const int tid  = threadIdx.x;
    const int blk  = blockIdx.x;        // 64
    const int e    = blk >> 5;
    const int dir  = (blk >> 4) & 1;
    const int b0   = (blk & 15) * 4;
    const int lane = tid & 63;
    const int l15  = lane & 15;
    const int lg   = lane >> 4;
    const int c    = l15 & 3;           // seq column
    const int q    = l15 >> 2;          // owned r-slot (gate split)
    const int jbase = (tid >> 6) * 16;
    const int j_own = jbase + lg * 4 + q;

    for (int u = tid; u < 512; u += 448)
        ((unsigned int*)h_lds)[u] = 0u;

    // stage enc slice into LDS (content chunk = rc ^ (c<<2))
    #pragma unroll
    for (int i = 0; i < 19; ++i) {
        const int s = tid + i * 448;
        if (s < 8192) {
            const int sc = s >> 11, st = (s >> 4) & 127, rc = s & 15;
            const int gch = rc ^ (sc << 2);
            const u32x4 v = *(const u32x4*)(enc_bf
                + ((size_t)e * NTREE + st * 64 + b0 + sc) * EE + gch * 8);
            *(u32x4*)(enc_lds + s * 16) = v;
        }
    }

    // weight A-frags: row j = jbase + l15, k = ks*32 + lg*8
    bf8 aI[3][4], aH[3][4];
    {
        const unsigned short* wiP = wih_pad + (size_t)dir * 3 * 128 * 128;
        const unsigned short* whP = whh_pad + (size_t)dir * 3 * 128 * 128;
        #pragma unroll
        for (int g = 0; g < 3; ++g)
            #pragma unroll
            for (int ks = 0; ks < 4; ++ks) {
                const size_t ro = (size_t)(g * 128 + jbase + l15) * 128 + ks * 32 + lg * 8;
                aI[g][ks] = *(const bf8*)(wiP + ro);
                aH[g][ks] = *(const bf8*)(whP + ro);
            }
    }
    const float* __restrict__ bih = dir ? bih_b : bih_f;
    const float* __restrict__ bhh = dir ? bhh_b : bhh_f;
    f32x4 bR, bZ, bI_, bH_;
    #pragma unroll
    for (int r = 0; r < 4; ++r) {
        const int j = jbase + lg * 4 + r;
        bR[r]  = (j < 100) ? bih[j]       + bhh[j]       : 0.f;
        bZ[r]  = (j < 100) ? bih[100 + j] + bhh[100 + j] : 0.f;
        bI_[r] = (j < 100) ? bih[200 + j] : 0.f;
        bH_[r] = (j < 100) ? bhh[200 + j] : 0.f;
    }

    // constant per-lane LDS offsets
    unsigned int eoff[4], hoff[4];
    #pragma unroll
    for (int ks = 0; ks < 4; ++ks) {
        eoff[ks] = c * 32768 + ((((ks * 4 + lg) ^ (c << 2)) & 15) << 4);
        hoff[ks] = c * 256 + (((ks * 4 + lg + 4 * c) & 15) << 4);
    }
    const unsigned int hw_off = c * 256
        + ((((j_own >> 3) + 4 * c) & 15) << 4) + (j_own & 7) * 2;

    float h_cur = 0.f;
    float hmx   = -1e30f;
    __syncthreads();   // staging + h-zero complete (one-time drain)

    bf8 eC[4], eN[4];
    {
        const int tm = dir ? 127 : 0;
        #pragma unroll
        for (int ks = 0; ks < 4; ++ks)
            eC[ks] = *(const bf8*)(enc_lds + tm * 256 + eoff[ks]);
    }

#define L2E  1.4426950408889634f
#define GRU_STEP(EC, EN, P, S)                                                 \
    {                                                                          \
        bf8 hF[4];                                                             \
        _Pragma("unroll")                                                      \
        for (int ks = 0; ks < 4; ++ks)                                         \
            hF[ks] = *(const bf8*)(h_lds[P] + hoff[ks]);                       \
        f32x4 ar = bR, az = bZ, ai = bI_, ah = bH_;                            \
        _Pragma("unroll")                                                      \
        for (int ks = 0; ks < 4; ++ks) {                                       \
            ar = __builtin_amdgcn_mfma_f32_16x16x32_bf16(aI[0][ks], EC[ks], ar, 0, 0, 0); \
            az = __builtin_amdgcn_mfma_f32_16x16x32_bf16(aI[1][ks], EC[ks], az, 0, 0, 0); \
            ai = __builtin_amdgcn_mfma_f32_16x16x32_bf16(aI[2][ks], EC[ks], ai, 0, 0, 0); \
        }                                                                      \
        if ((S) + 1 < S_) {                                                    \
            const int tmn = dir ? (126 - (S)) : ((S) + 1);                     \
            _Pragma("unroll")                                                  \
            for (int ks = 0; ks < 4; ++ks)                                     \
                EN[ks] = *(const bf8*)(enc_lds + tmn * 256 + eoff[ks]);        \
        }                                                                      \
        _Pragma("unroll")                                                      \
        for (int ks = 0; ks < 4; ++ks) {                                       \
            ar = __builtin_amdgcn_mfma_f32_16x16x32_bf16(aH[0][ks], hF[ks], ar, 0, 0, 0); \
            az = __builtin_amdgcn_mfma_f32_16x16x32_bf16(aH[1][ks], hF[ks], az, 0, 0, 0); \
            ah = __builtin_amdgcn_mfma_f32_16x16x32_bf16(aH[2][ks], hF[ks], ah, 0, 0, 0); \
        }                                                                      \
        const float gr  = selq(ar, q);                                         \
        const float gz  = selq(az, q);                                         \
        const float gi_ = selq(ai, q);                                         \
        const float gh_ = selq(ah, q);                                         \
        const float rg  = __builtin_amdgcn_rcpf(1.f + __builtin_amdgcn_exp2f(-L2E * gr)); \
        const float zg  = __builtin_amdgcn_rcpf(1.f + __builtin_amdgcn_exp2f(-L2E * gz)); \
        const float nx  = gi_ + rg * gh_;                                      \
        const float ng  = 1.f - 2.f * __builtin_amdgcn_rcpf(1.f + __builtin_amdgcn_exp2f((2.f * L2E) * nx)); \
        const float hnew = ng + zg * (h_cur - ng);                             \
        h_cur = hnew;                                                          \
        hmx = fmaxf(hmx, hnew);                                                \
        *(unsigned short*)(h_lds[(P) ^ 1] + hw_off) = f2bf(hnew);              \
        __builtin_amdgcn_sched_barrier(0);                                     \
        asm volatile("s_waitcnt lgkmcnt(0)");                                  \
        __builtin_amdgcn_s_barrier();                                          \
        __builtin_amdgcn_sched_barrier(0);                                     \
    }

    for (int t = 0; t < S_; t += 2) {
        GRU_STEP(eC, eN, 0, t)
        GRU_STEP(eN, eC, 1, t + 1)
    }
#undef GRU_STEP

    if (j_own < 100)
        hmax_out[((size_t)((e * 2 + dir) * 64 + b0 + c)) * HH + j_own] = hmx;
}

// ---------------------------------------------------------------------------
// K4: fc + softmax — parallel (unchanged from R14).
// ---------------------------------------------------------------------------
__global__ __launch_bounds__(512) void k_final(
    const float* __restrict__ hmax,
    const float* __restrict__ fcw,
    const float* __restrict__ fcb,
    float* __restrict__ out)
{
    const int tid  = threadIdx.x;
    const int b    = tid >> 3;
    const int part = tid & 7;
    float y0 = 0.f, y1 = 0.f;
    #pragma unroll 2
    for (int i = 0; i < 50; ++i) {
        const int m   = part * 50 + i;
        const int e   = m / 200;
        const int dm  = m % 200;
        const int dir = dm / 100;
        const int j   = dm % 100;
        const float x = hmax[((size_t)((e * 2 + dir) * 64 + b)) * HH + j];
        y0 += fcw[m]       * x;
        y1 += fcw[400 + m] * x;
    }
    #pragma unroll
    for (int m = 1; m < 8; m <<= 1) {
        y0 += __shfl_xor(y0, m);
        y1 += __shfl_xor(y1, m);
    }
    if (part == 0) {
        y0 += fcb[0]; y1 += fcb[1];
        const float mx = fmaxf(y0, y1);
        const float e0 = __expf(y0 - mx), e1 = __expf(y1 - mx);
        const float s = e0 + e1;
        out[b * 2]     = e0 / s;
        out[b * 2 + 1] = e1 / s;
    }
}

extern "C" void kernel_launch(void* const* d_in, const int* in_sizes, int n_in,
                              void* d_out, int out_size, void* d_ws, size_t ws_size,
                              hipStream_t stream)
{
    const int*   tok1  = (const int*)d_in[0];
    const int*   tok2  = (const int*)d_in[1];
    const float* emb   = (const float*)d_in[4];
    const float* Wc    = (const float*)d_in[5];
    const float* bc    = (const float*)d_in[6];
    const float* wih_f = (const float*)d_in[7];
    const float* whh_f = (const float*)d_in[8];
    const float* bih_f = (const float*)d_in[9];
    const float* bhh_f = (const float*)d_in[10];
    const float* wih_b = (const float*)d_in[11];
    const float* whh_b = (const float*)d_in[12];
    const float* bih_b = (const float*)d_in[13];
    const float* bhh_b = (const float*)d_in[14];
    const float* fcw   = (const float*)d_in[15];
    const float* fcb   = (const float*)d_in[16];

    char* ws = (char*)d_ws;
    unsigned short* emb_bf  = (unsigned short*)(ws + EMB_BF_OFF);
    unsigned short* wc_bf   = (unsigned short*)(ws + WC_BF_OFF);
    unsigned short* wih_pad = (unsigned short*)(ws + WIH_BF_OFF);
    unsigned short* whh_pad = (unsigned short*)(ws + WHH_BF_OFF);
    unsigned short* enc_bf  = (unsigned short*)(ws + ENC_BF_OFF);
    float*          hmax    = (float*)(ws + HMAX_OFF);

    k_prep<<<6458, 256, 0, stream>>>(emb, Wc, wih_f, wih_b, whh_f, whh_b,
                                     emb_bf, wc_bf, wih_pad, whh_pad);
    k_encode<<<2048, 512, 0, stream>>>(tok1, tok2, emb_bf, wc_bf, bc, enc_bf);
    k_gru<<<64, 448, 0, stream>>>(enc_bf, wih_pad, whh_pad,
                                  bih_f, bih_b, bhh_f, bhh_b, hmax);
    k_final<<<1, 512, 0, stream>>>(hmax, fcw, fcb, (float*)d_out);
}